// Round 14
// baseline (228.033 us; speedup 1.0000x reference)
//
#include <hip/hip_runtime.h>

#define NROWS 8192
#define NCOLS 4096
#define LAMB  0.1
#define NBUCK 2048

typedef unsigned int u32;
typedef unsigned long long u64;

// ---------------------------------------------------------------------------
// Kernel 1: per-row squared error sum. ONE 256-THREAD BLOCK PER ROW (R10
// structure, ~41 us in-bench). NEW: block 0's thread 0 also publishes the
// row's bit pattern to global atomicMin/Max (monotone for err >= 0), so the
// tail kernel needs no min/max pass.
// ---------------------------------------------------------------------------
__global__ __launch_bounds__(256) void rowerr_kernel(const float* __restrict__ inp,
                                                     const float* __restrict__ tgt,
                                                     float* __restrict__ err,
                                                     u32* __restrict__ minmax) {
    const int row = blockIdx.x;
    const float4* a = reinterpret_cast<const float4*>(inp + (size_t)row * NCOLS);
    const float4* b = reinterpret_cast<const float4*>(tgt + (size_t)row * NCOLS);
    const int t = threadIdx.x;

    float acc = 0.f;
#pragma unroll
    for (int c = 0; c < 4; ++c) {
        float4 va = a[t + c * 256];
        float4 vb = b[t + c * 256];
        float dx = va.x - vb.x;
        float dy = va.y - vb.y;
        float dz = va.z - vb.z;
        float dw = va.w - vb.w;
        acc += dx * dx + dy * dy + dz * dz + dw * dw;
    }

#pragma unroll
    for (int off = 32; off > 0; off >>= 1) acc += __shfl_down(acc, off, 64);

    __shared__ float ws[4];
    const int lane = t & 63, wv = t >> 6;
    if (lane == 0) ws[wv] = acc;
    __syncthreads();
    if (t == 0) {
        const float v = ws[0] + ws[1] + ws[2] + ws[3];
        err[row] = v;
        const u32 bits = __float_as_uint(v);
        atomicMin(&minmax[0], bits);     // fire-and-forget device atomics
        atomicMax(&minmax[1], bits);
    }
}

// ---------------------------------------------------------------------------
// fast f64 reciprocal: f32 seed + 2 Newton steps (~1 ulp, no f64 divide)
// ---------------------------------------------------------------------------
__device__ __forceinline__ double fastrcp(double x) {
    double r = (double)(1.0f / (float)x);
    r = r * (2.0 - x * r);
    r = r * (2.0 - x * r);
    return r;
}

// ---------------------------------------------------------------------------
// Kernel 2: single block, 1024 threads. Bucket sort + exact rank, IN PLACE:
//   min/max come precomputed from kernel 1 (no global re-read phase).
//   1. zero hist; stage err as float4 -> biased bits, bucket ids
//   2. LDS-atomic histogram
//   3. exclusive scan of 2048 counts -> base2; cursors into hist
//   4. scatter via atomic cursor (returned offset = tie-break order)
//   5. exact in-bucket rank (reads only) -> barrier -> in-place write
//   6. obj phase: f64 scan of cs, total of cs2, argmax of
//      h(k) = cs^2/k + (total-cs)^2/(n-k)   (== argmin (Sw1+Sw2)/Sb)
// LDS ~44 KB. Exact permutation for any input.
// ---------------------------------------------------------------------------
__global__ __launch_bounds__(1024) void drae_kernel(const float* __restrict__ err,
                                                    const u32* __restrict__ minmax,
                                                    float* __restrict__ out) {
    const int N = NROWS;
    __shared__ u32 bufB[NROWS];            // 32 KB  scattered -> sorted (in place)
    __shared__ u32 hist[NBUCK];            // 8 KB   counts -> cursors -> ends
    __shared__ u32 base2[NBUCK];           // 8 KB   segment starts
    __shared__ u32 saux[16];
    __shared__ double auxX[16], auxT2[16], redH[16], redCs[16];
    __shared__ int    redIdx[16];

    const int tid  = threadIdx.x;
    const int lane = tid & 63, wv = tid >> 6;

    // ---- zero hist, load min/max, stage err (float4), bucketize ----
    hist[tid] = 0;
    hist[tid + 1024] = 0;

    const u32 minb = minmax[0];
    const u32 maxb = minmax[1];
    const u32 range = maxb - minb;
    const int nbits = 32 - __clz(range | 1u);          // >= 1
    const int shift = (nbits > 11) ? (nbits - 11) : 0; // bucket < 2048

    u32 bits[8];
    {
        const float4* e4 = reinterpret_cast<const float4*>(err);
        const float4 f0 = e4[tid];
        const float4 f1 = e4[tid + 1024];
        bits[0] = __float_as_uint(f0.x) - minb;
        bits[1] = __float_as_uint(f0.y) - minb;
        bits[2] = __float_as_uint(f0.z) - minb;
        bits[3] = __float_as_uint(f0.w) - minb;
        bits[4] = __float_as_uint(f1.x) - minb;
        bits[5] = __float_as_uint(f1.y) - minb;
        bits[6] = __float_as_uint(f1.z) - minb;
        bits[7] = __float_as_uint(f1.w) - minb;
    }
    u32 bk[8];
#pragma unroll
    for (int k = 0; k < 8; ++k) bk[k] = bits[k] >> shift;

    __syncthreads();                       // hist zeroed everywhere

    // ---- histogram ----
#pragma unroll
    for (int k = 0; k < 8; ++k) atomicAdd(&hist[bk[k]], 1u);
    __syncthreads();

    // ---- exclusive scan of 2048 counts (2 per thread) ----
    const u32 c0 = hist[2 * tid], c1 = hist[2 * tid + 1];
    const u32 tsum = c0 + c1;
    u32 incl = tsum;
#pragma unroll
    for (int off = 1; off < 64; off <<= 1) {
        const u32 t = __shfl_up(incl, off, 64);
        if (lane >= off) incl += t;
    }
    if (lane == 63) saux[wv] = incl;
    __syncthreads();                       // all hist reads + saux done
    u32 add = 0;
#pragma unroll
    for (int w = 0; w < 16; ++w) if (w < wv) add += saux[w];
    const u32 excl = add + incl - tsum;
    base2[2 * tid] = excl;           base2[2 * tid + 1] = excl + c0;
    hist[2 * tid]  = excl;           hist[2 * tid + 1]  = excl + c0;   // cursors
    __syncthreads();

    // ---- scatter; atomic cursor return = tie-break order within bucket ----
    u32 myq[8];
#pragma unroll
    for (int k = 0; k < 8; ++k) {
        const u32 p = atomicAdd(&hist[bk[k]], 1u);
        myq[k] = p - base2[bk[k]];
        bufB[p] = bits[k];
    }
    __syncthreads();                       // hist[b] is now segment END

    // ---- exact rank within bucket (reads only) ----
    u32 pos[8];
#pragma unroll
    for (int k = 0; k < 8; ++k) {
        const u32 s = base2[bk[k]];
        const u32 e = hist[bk[k]];
        const u32 ki = bits[k];
        u32 r = 0;
        for (u32 q = 0; q < e - s; ++q) {
            const u32 v = bufB[s + q];
            r += (v < ki || (v == ki && q < myq[k])) ? 1u : 0u;
        }
        pos[k] = s + r;
    }
    __syncthreads();                       // all rank reads complete

    // ---- in-place sorted write ----
#pragma unroll
    for (int k = 0; k < 8; ++k) bufB[pos[k]] = bits[k];
    __syncthreads();                       // bufB fully sorted (biased keys)

    // ================= obj phase ==========================================
    float v[8];
#pragma unroll
    for (int r = 0; r < 8; ++r) v[r] = __uint_as_float(bufB[(tid << 3) + r] + minb);

    double sx = 0.0, sx2 = 0.0;
#pragma unroll
    for (int r = 0; r < 8; ++r) {
        sx  += (double)v[r];
        sx2 += (double)v[r] * (double)v[r];
    }

    // wave inclusive scan of sx; wave total of sx2
    double ix = sx;
#pragma unroll
    for (int off = 1; off < 64; off <<= 1) {
        double t1 = __shfl_up(ix, off, 64);
        if (lane >= off) ix += t1;
    }
    double t2 = sx2;
#pragma unroll
    for (int off = 32; off > 0; off >>= 1) t2 += __shfl_xor(t2, off, 64);

    if (lane == 63) auxX[wv]  = ix;
    if (lane == 0)  auxT2[wv] = t2;
    __syncthreads();

    double wOff1 = 0.0, total1 = 0.0, total2 = 0.0;
#pragma unroll
    for (int w = 0; w < 16; ++w) {
        const double a1 = auxX[w];
        if (w < wv) wOff1 += a1;
        total1 += a1;
        total2 += auxT2[w];
    }
    const double exc1 = wOff1 + (ix - sx);
    const double nf = (double)N;

    // on-the-fly h(k) + local argmax (== argmin obj), first index on ties
    double run1 = exc1;
    double bestH = -1e300, bestCs = 0.0;
    int bestIdx = N;
#pragma unroll
    for (int r = 0; r < 8; ++r) {
        const int idx = (tid << 3) + r;
        run1 += (double)v[r];
        if (idx < N - 1) {
            const double kf  = (double)(idx + 1);
            const double rem = total1 - run1;
            const double h   = run1 * run1 * fastrcp(kf) +
                               rem  * rem  * fastrcp(nf - kf);
            if (h > bestH) { bestH = h; bestIdx = idx; bestCs = run1; }
        }
    }

    // wave argmax reduce (max h, first index on ties)
#pragma unroll
    for (int off = 32; off > 0; off >>= 1) {
        const double oH   = __shfl_down(bestH, off, 64);
        const int    oIdx = __shfl_down(bestIdx, off, 64);
        const double oCs  = __shfl_down(bestCs, off, 64);
        if (oH > bestH || (oH == bestH && oIdx < bestIdx)) {
            bestH = oH; bestIdx = oIdx; bestCs = oCs;
        }
    }
    if (lane == 0) { redH[wv] = bestH; redIdx[wv] = bestIdx; redCs[wv] = bestCs; }
    __syncthreads();

    if (tid == 0) {
        double bH = redH[0], bCs = redCs[0];
        int bIdx = redIdx[0];
        for (int w = 1; w < 16; ++w) {
            if (redH[w] > bH || (redH[w] == bH && redIdx[w] < bIdx)) {
                bH = redH[w]; bIdx = redIdx[w]; bCs = redCs[w];
            }
        }
        const double Sb     = total2 - total1 * total1 / nf;
        const double optObj = (total2 - bH) / Sb;
        const double T      = (double)(bIdx + 1);
        out[0] = (float)(bCs / T + LAMB * optObj);
    }
}

// ---------------------------------------------------------------------------
extern "C" void kernel_launch(void* const* d_in, const int* in_sizes, int n_in,
                              void* d_out, int out_size, void* d_ws, size_t ws_size,
                              hipStream_t stream) {
    const float* inp = (const float*)d_in[0];
    const float* tgt = (const float*)d_in[1];
    float* errbuf = (float*)d_ws;                        // 8192 f32 = 32 KB
    u32*   minmax = (u32*)((char*)d_ws + NROWS * 4);     // 2 x u32

    hipMemsetAsync(&minmax[0], 0xFF, 4, stream);         // min = 0xFFFFFFFF
    hipMemsetAsync(&minmax[1], 0x00, 4, stream);         // max = 0
    rowerr_kernel<<<NROWS, 256, 0, stream>>>(inp, tgt, errbuf, minmax);
    drae_kernel<<<1, 1024, 0, stream>>>(errbuf, minmax, (float*)d_out);
}

// Round 15
// 69.541 us; speedup vs baseline: 3.2791x; 3.2791x over previous
//
#include <hip/hip_runtime.h>

#define NROWS 8192
#define NCOLS 4096
#define LAMB  0.1
#define NBUCK 2048

typedef unsigned int u32;
typedef unsigned long long u64;

// ---------------------------------------------------------------------------
// Kernel 1: per-row squared error sum. ONE 256-THREAD BLOCK PER ROW.
// Byte-identical to R10/R13 (~41 us in-bench, warm L3). NO global atomics:
// R14 proved 16K same-address device atomics serialize (~+100 us).
// ---------------------------------------------------------------------------
__global__ __launch_bounds__(256) void rowerr_kernel(const float* __restrict__ inp,
                                                     const float* __restrict__ tgt,
                                                     float* __restrict__ err) {
    const int row = blockIdx.x;
    const float4* a = reinterpret_cast<const float4*>(inp + (size_t)row * NCOLS);
    const float4* b = reinterpret_cast<const float4*>(tgt + (size_t)row * NCOLS);
    const int t = threadIdx.x;

    float acc = 0.f;
#pragma unroll
    for (int c = 0; c < 4; ++c) {
        float4 va = a[t + c * 256];
        float4 vb = b[t + c * 256];
        float dx = va.x - vb.x;
        float dy = va.y - vb.y;
        float dz = va.z - vb.z;
        float dw = va.w - vb.w;
        acc += dx * dx + dy * dy + dz * dz + dw * dw;
    }

#pragma unroll
    for (int off = 32; off > 0; off >>= 1) acc += __shfl_down(acc, off, 64);

    __shared__ float ws[4];
    const int lane = t & 63, wv = t >> 6;
    if (lane == 0) ws[wv] = acc;
    __syncthreads();
    if (t == 0) err[row] = ws[0] + ws[1] + ws[2] + ws[3];
}

// ---------------------------------------------------------------------------
// fast f64 reciprocal: f32 seed + 2 Newton steps (~1 ulp, no f64 divide)
// ---------------------------------------------------------------------------
__device__ __forceinline__ double fastrcp(double x) {
    double r = (double)(1.0f / (float)x);
    r = r * (2.0 - x * r);
    r = r * (2.0 - x * r);
    return r;
}

// ---------------------------------------------------------------------------
// Kernel 2: single block, 1024 threads. Bucket sort + exact rank, IN PLACE.
//   1. float4-stage err -> regs; min/max via shuffle (cheap, ~1 us)
//   2. LDS-atomic histogram over 2048 buckets (top-11-bits of range)
//   3. exclusive scan of counts -> base2; cursors in hist
//   4. scatter via atomic cursor (returned offset = tie-break order)
//   5. exact in-bucket rank (reads only) -> barrier -> in-place write
//   6. obj phase: f64 scan of cs, total of cs2, argmax of
//      h(k) = cs^2/k + (total-cs)^2/(n-k)   (== argmin (Sw1+Sw2)/Sb)
// LDS ~44 KB. Exact permutation for any input (degenerate = slower, exact).
// ---------------------------------------------------------------------------
__global__ __launch_bounds__(1024) void drae_kernel(const float* __restrict__ err,
                                                    float* __restrict__ out) {
    const int N = NROWS;
    __shared__ u32 bufB[NROWS];            // 32 KB  scattered -> sorted (in place)
    __shared__ u32 hist[NBUCK];            // 8 KB   counts -> cursors -> ends
    __shared__ u32 base2[NBUCK];           // 8 KB   segment starts
    __shared__ u32 sMin[16], sMax[16], saux[16];
    __shared__ double auxX[16], auxT2[16], redH[16], redCs[16];
    __shared__ int    redIdx[16];

    const int tid  = threadIdx.x;
    const int lane = tid & 63, wv = tid >> 6;

    // ---- stage err as float4 -> regs; min/max; zero hist ----
    u32 bits[8];
    {
        const float4* e4 = reinterpret_cast<const float4*>(err);
        const float4 f0 = e4[tid];
        const float4 f1 = e4[tid + 1024];
        bits[0] = __float_as_uint(f0.x);
        bits[1] = __float_as_uint(f0.y);
        bits[2] = __float_as_uint(f0.z);
        bits[3] = __float_as_uint(f0.w);
        bits[4] = __float_as_uint(f1.x);
        bits[5] = __float_as_uint(f1.y);
        bits[6] = __float_as_uint(f1.z);
        bits[7] = __float_as_uint(f1.w);
    }
    u32 mn = 0xFFFFFFFFu, mx = 0u;
#pragma unroll
    for (int k = 0; k < 8; ++k) { mn = min(mn, bits[k]); mx = max(mx, bits[k]); }
#pragma unroll
    for (int off = 32; off > 0; off >>= 1) {
        mn = min(mn, (u32)__shfl_xor((int)mn, off, 64));
        mx = max(mx, (u32)__shfl_xor((int)mx, off, 64));
    }
    if (lane == 0) { sMin[wv] = mn; sMax[wv] = mx; }

    hist[tid] = 0;
    hist[tid + 1024] = 0;
    __syncthreads();

    u32 minb = sMin[0], maxb = sMax[0];
#pragma unroll
    for (int w = 1; w < 16; ++w) { minb = min(minb, sMin[w]); maxb = max(maxb, sMax[w]); }
    const u32 range = maxb - minb;
    const int nbits = 32 - __clz(range | 1u);          // >= 1
    const int shift = (nbits > 11) ? (nbits - 11) : 0; // bucket < 2048

    u32 bk[8];
#pragma unroll
    for (int k = 0; k < 8; ++k) {
        bits[k] -= minb;
        bk[k] = bits[k] >> shift;
        atomicAdd(&hist[bk[k]], 1u);
    }
    __syncthreads();

    // ---- exclusive scan of 2048 counts (2 per thread) ----
    const u32 c0 = hist[2 * tid], c1 = hist[2 * tid + 1];
    const u32 tsum = c0 + c1;
    u32 incl = tsum;
#pragma unroll
    for (int off = 1; off < 64; off <<= 1) {
        const u32 t = __shfl_up(incl, off, 64);
        if (lane >= off) incl += t;
    }
    if (lane == 63) saux[wv] = incl;
    __syncthreads();                       // all hist reads + saux done
    u32 add = 0;
#pragma unroll
    for (int w = 0; w < 16; ++w) if (w < wv) add += saux[w];
    const u32 excl = add + incl - tsum;
    base2[2 * tid] = excl;           base2[2 * tid + 1] = excl + c0;
    hist[2 * tid]  = excl;           hist[2 * tid + 1]  = excl + c0;   // cursors
    __syncthreads();

    // ---- scatter; atomic cursor return = tie-break order within bucket ----
    u32 myq[8];
#pragma unroll
    for (int k = 0; k < 8; ++k) {
        const u32 p = atomicAdd(&hist[bk[k]], 1u);
        myq[k] = p - base2[bk[k]];
        bufB[p] = bits[k];
    }
    __syncthreads();                       // hist[b] is now segment END

    // ---- exact rank within bucket (reads only) ----
    u32 pos[8];
#pragma unroll
    for (int k = 0; k < 8; ++k) {
        const u32 s = base2[bk[k]];
        const u32 e = hist[bk[k]];
        const u32 ki = bits[k];
        u32 r = 0;
        for (u32 q = 0; q < e - s; ++q) {
            const u32 v = bufB[s + q];
            r += (v < ki || (v == ki && q < myq[k])) ? 1u : 0u;
        }
        pos[k] = s + r;
    }
    __syncthreads();                       // all rank reads complete

    // ---- in-place sorted write ----
#pragma unroll
    for (int k = 0; k < 8; ++k) bufB[pos[k]] = bits[k];
    __syncthreads();                       // bufB fully sorted (biased keys)

    // ================= obj phase ==========================================
    float v[8];
#pragma unroll
    for (int r = 0; r < 8; ++r) v[r] = __uint_as_float(bufB[(tid << 3) + r] + minb);

    double sx = 0.0, sx2 = 0.0;
#pragma unroll
    for (int r = 0; r < 8; ++r) {
        sx  += (double)v[r];
        sx2 += (double)v[r] * (double)v[r];
    }

    // wave inclusive scan of sx; wave total of sx2
    double ix = sx;
#pragma unroll
    for (int off = 1; off < 64; off <<= 1) {
        double t1 = __shfl_up(ix, off, 64);
        if (lane >= off) ix += t1;
    }
    double t2 = sx2;
#pragma unroll
    for (int off = 32; off > 0; off >>= 1) t2 += __shfl_xor(t2, off, 64);

    if (lane == 63) auxX[wv]  = ix;
    if (lane == 0)  auxT2[wv] = t2;
    __syncthreads();

    double wOff1 = 0.0, total1 = 0.0, total2 = 0.0;
#pragma unroll
    for (int w = 0; w < 16; ++w) {
        const double a1 = auxX[w];
        if (w < wv) wOff1 += a1;
        total1 += a1;
        total2 += auxT2[w];
    }
    const double exc1 = wOff1 + (ix - sx);
    const double nf = (double)N;

    // on-the-fly h(k) + local argmax (== argmin obj), first index on ties
    double run1 = exc1;
    double bestH = -1e300, bestCs = 0.0;
    int bestIdx = N;
#pragma unroll
    for (int r = 0; r < 8; ++r) {
        const int idx = (tid << 3) + r;
        run1 += (double)v[r];
        if (idx < N - 1) {
            const double kf  = (double)(idx + 1);
            const double rem = total1 - run1;
            const double h   = run1 * run1 * fastrcp(kf) +
                               rem  * rem  * fastrcp(nf - kf);
            if (h > bestH) { bestH = h; bestIdx = idx; bestCs = run1; }
        }
    }

    // wave argmax reduce (max h, first index on ties)
#pragma unroll
    for (int off = 32; off > 0; off >>= 1) {
        const double oH   = __shfl_down(bestH, off, 64);
        const int    oIdx = __shfl_down(bestIdx, off, 64);
        const double oCs  = __shfl_down(bestCs, off, 64);
        if (oH > bestH || (oH == bestH && oIdx < bestIdx)) {
            bestH = oH; bestIdx = oIdx; bestCs = oCs;
        }
    }
    if (lane == 0) { redH[wv] = bestH; redIdx[wv] = bestIdx; redCs[wv] = bestCs; }
    __syncthreads();

    if (tid == 0) {
        double bH = redH[0], bCs = redCs[0];
        int bIdx = redIdx[0];
        for (int w = 1; w < 16; ++w) {
            if (redH[w] > bH || (redH[w] == bH && redIdx[w] < bIdx)) {
                bH = redH[w]; bIdx = redIdx[w]; bCs = redCs[w];
            }
        }
        const double Sb     = total2 - total1 * total1 / nf;
        const double optObj = (total2 - bH) / Sb;
        const double T      = (double)(bIdx + 1);
        out[0] = (float)(bCs / T + LAMB * optObj);
    }
}

// ---------------------------------------------------------------------------
extern "C" void kernel_launch(void* const* d_in, const int* in_sizes, int n_in,
                              void* d_out, int out_size, void* d_ws, size_t ws_size,
                              hipStream_t stream) {
    const float* inp = (const float*)d_in[0];
    const float* tgt = (const float*)d_in[1];
    float* errbuf = (float*)d_ws;   // 8192 f32 = 32 KB scratch

    rowerr_kernel<<<NROWS, 256, 0, stream>>>(inp, tgt, errbuf);
    drae_kernel<<<1, 1024, 0, stream>>>(errbuf, (float*)d_out);
}

// Round 16
// 68.765 us; speedup vs baseline: 3.3161x; 1.0113x over previous
//
#include <hip/hip_runtime.h>

#define NROWS 8192
#define NCOLS 4096
#define LAMB  0.1
#define NBUCK 2048

typedef unsigned int u32;
typedef unsigned long long u64;

// ---------------------------------------------------------------------------
// Kernel 1: per-row squared error sum. ONE 256-THREAD BLOCK PER ROW.
// Byte-identical to R10/R13 (~41 us in-bench, warm L3).
// ---------------------------------------------------------------------------
__global__ __launch_bounds__(256) void rowerr_kernel(const float* __restrict__ inp,
                                                     const float* __restrict__ tgt,
                                                     float* __restrict__ err) {
    const int row = blockIdx.x;
    const float4* a = reinterpret_cast<const float4*>(inp + (size_t)row * NCOLS);
    const float4* b = reinterpret_cast<const float4*>(tgt + (size_t)row * NCOLS);
    const int t = threadIdx.x;

    float acc = 0.f;
#pragma unroll
    for (int c = 0; c < 4; ++c) {
        float4 va = a[t + c * 256];
        float4 vb = b[t + c * 256];
        float dx = va.x - vb.x;
        float dy = va.y - vb.y;
        float dz = va.z - vb.z;
        float dw = va.w - vb.w;
        acc += dx * dx + dy * dy + dz * dz + dw * dw;
    }

#pragma unroll
    for (int off = 32; off > 0; off >>= 1) acc += __shfl_down(acc, off, 64);

    __shared__ float ws[4];
    const int lane = t & 63, wv = t >> 6;
    if (lane == 0) ws[wv] = acc;
    __syncthreads();
    if (t == 0) err[row] = ws[0] + ws[1] + ws[2] + ws[3];
}

// ---------------------------------------------------------------------------
// fast f64 reciprocal: f32 seed + 2 Newton steps (~1 ulp, no f64 divide)
// ---------------------------------------------------------------------------
__device__ __forceinline__ double fastrcp(double x) {
    double r = (double)(1.0f / (float)x);
    r = r * (2.0 - x * r);
    r = r * (2.0 - x * r);
    return r;
}

// ---------------------------------------------------------------------------
// Kernel 2: 256 DUPLICATE blocks x 1024 threads. Every block independently
// runs the identical LDS-local bucket sort + obj phase (no tickets, no
// fences, no cross-block traffic); only block 0 writes out[0].
// Rationale: a 1-block tail leaves 255 CUs idle -> low DVFS clocks / poor
// latency hiding made ~4 us of work cost ~22 us. Duplicating the work keeps
// the chip busy; duration stays ~= one block's time.
//   1. float4-stage err -> regs; min/max via shuffle
//   2. LDS-atomic histogram over 2048 buckets (top-11-bits of range)
//   3. exclusive scan -> segment bases; cursors
//   4. scatter via atomic cursor (returned offset = tie-break order)
//   5. exact in-bucket rank (reads only) -> barrier -> in-place write
//   6. obj: f64 scan of cs, total of cs2, argmax of
//      h(k) = cs^2/k + (total-cs)^2/(n-k)   (== argmin (Sw1+Sw2)/Sb)
// ---------------------------------------------------------------------------
__global__ __launch_bounds__(1024) void drae_kernel(const float* __restrict__ err,
                                                    float* __restrict__ out) {
    const int N = NROWS;
    __shared__ u32 bufB[NROWS];            // 32 KB  scattered -> sorted (in place)
    __shared__ u32 hist[NBUCK];            // 8 KB   counts -> cursors -> ends
    __shared__ u32 base2[NBUCK];           // 8 KB   segment starts
    __shared__ u32 sMin[16], sMax[16], saux[16];
    __shared__ double auxX[16], auxT2[16], redH[16], redCs[16];
    __shared__ int    redIdx[16];

    const int tid  = threadIdx.x;
    const int lane = tid & 63, wv = tid >> 6;

    // ---- stage err as float4 -> regs; min/max; zero hist ----
    u32 bits[8];
    {
        const float4* e4 = reinterpret_cast<const float4*>(err);
        const float4 f0 = e4[tid];
        const float4 f1 = e4[tid + 1024];
        bits[0] = __float_as_uint(f0.x);
        bits[1] = __float_as_uint(f0.y);
        bits[2] = __float_as_uint(f0.z);
        bits[3] = __float_as_uint(f0.w);
        bits[4] = __float_as_uint(f1.x);
        bits[5] = __float_as_uint(f1.y);
        bits[6] = __float_as_uint(f1.z);
        bits[7] = __float_as_uint(f1.w);
    }
    u32 mn = 0xFFFFFFFFu, mx = 0u;
#pragma unroll
    for (int k = 0; k < 8; ++k) { mn = min(mn, bits[k]); mx = max(mx, bits[k]); }
#pragma unroll
    for (int off = 32; off > 0; off >>= 1) {
        mn = min(mn, (u32)__shfl_xor((int)mn, off, 64));
        mx = max(mx, (u32)__shfl_xor((int)mx, off, 64));
    }
    if (lane == 0) { sMin[wv] = mn; sMax[wv] = mx; }

    hist[tid] = 0;
    hist[tid + 1024] = 0;
    __syncthreads();

    u32 minb = sMin[0], maxb = sMax[0];
#pragma unroll
    for (int w = 1; w < 16; ++w) { minb = min(minb, sMin[w]); maxb = max(maxb, sMax[w]); }
    const u32 range = maxb - minb;
    const int nbits = 32 - __clz(range | 1u);          // >= 1
    const int shift = (nbits > 11) ? (nbits - 11) : 0; // bucket < 2048

    u32 bk[8];
#pragma unroll
    for (int k = 0; k < 8; ++k) {
        bits[k] -= minb;
        bk[k] = bits[k] >> shift;
        atomicAdd(&hist[bk[k]], 1u);
    }
    __syncthreads();

    // ---- exclusive scan of 2048 counts (2 per thread) ----
    const u32 c0 = hist[2 * tid], c1 = hist[2 * tid + 1];
    const u32 tsum = c0 + c1;
    u32 incl = tsum;
#pragma unroll
    for (int off = 1; off < 64; off <<= 1) {
        const u32 t = __shfl_up(incl, off, 64);
        if (lane >= off) incl += t;
    }
    if (lane == 63) saux[wv] = incl;
    __syncthreads();                       // all hist reads + saux done
    u32 add = 0;
#pragma unroll
    for (int w = 0; w < 16; ++w) if (w < wv) add += saux[w];
    const u32 excl = add + incl - tsum;
    base2[2 * tid] = excl;           base2[2 * tid + 1] = excl + c0;
    hist[2 * tid]  = excl;           hist[2 * tid + 1]  = excl + c0;   // cursors
    __syncthreads();

    // ---- scatter; atomic cursor return = tie-break order within bucket ----
    u32 myq[8];
#pragma unroll
    for (int k = 0; k < 8; ++k) {
        const u32 p = atomicAdd(&hist[bk[k]], 1u);
        myq[k] = p - base2[bk[k]];
        bufB[p] = bits[k];
    }
    __syncthreads();                       // hist[b] is now segment END

    // ---- exact rank within bucket (reads only) ----
    u32 pos[8];
#pragma unroll
    for (int k = 0; k < 8; ++k) {
        const u32 s = base2[bk[k]];
        const u32 e = hist[bk[k]];
        const u32 ki = bits[k];
        u32 r = 0;
        for (u32 q = 0; q < e - s; ++q) {
            const u32 v = bufB[s + q];
            r += (v < ki || (v == ki && q < myq[k])) ? 1u : 0u;
        }
        pos[k] = s + r;
    }
    __syncthreads();                       // all rank reads complete

    // ---- in-place sorted write ----
#pragma unroll
    for (int k = 0; k < 8; ++k) bufB[pos[k]] = bits[k];
    __syncthreads();                       // bufB fully sorted (biased keys)

    // ================= obj phase ==========================================
    float v[8];
#pragma unroll
    for (int r = 0; r < 8; ++r) v[r] = __uint_as_float(bufB[(tid << 3) + r] + minb);

    double sx = 0.0, sx2 = 0.0;
#pragma unroll
    for (int r = 0; r < 8; ++r) {
        sx  += (double)v[r];
        sx2 += (double)v[r] * (double)v[r];
    }

    // wave inclusive scan of sx; wave total of sx2
    double ix = sx;
#pragma unroll
    for (int off = 1; off < 64; off <<= 1) {
        double t1 = __shfl_up(ix, off, 64);
        if (lane >= off) ix += t1;
    }
    double t2 = sx2;
#pragma unroll
    for (int off = 32; off > 0; off >>= 1) t2 += __shfl_xor(t2, off, 64);

    if (lane == 63) auxX[wv]  = ix;
    if (lane == 0)  auxT2[wv] = t2;
    __syncthreads();

    double wOff1 = 0.0, total1 = 0.0, total2 = 0.0;
#pragma unroll
    for (int w = 0; w < 16; ++w) {
        const double a1 = auxX[w];
        if (w < wv) wOff1 += a1;
        total1 += a1;
        total2 += auxT2[w];
    }
    const double exc1 = wOff1 + (ix - sx);
    const double nf = (double)N;

    // on-the-fly h(k) + local argmax (== argmin obj), first index on ties
    double run1 = exc1;
    double bestH = -1e300, bestCs = 0.0;
    int bestIdx = N;
#pragma unroll
    for (int r = 0; r < 8; ++r) {
        const int idx = (tid << 3) + r;
        run1 += (double)v[r];
        if (idx < N - 1) {
            const double kf  = (double)(idx + 1);
            const double rem = total1 - run1;
            const double h   = run1 * run1 * fastrcp(kf) +
                               rem  * rem  * fastrcp(nf - kf);
            if (h > bestH) { bestH = h; bestIdx = idx; bestCs = run1; }
        }
    }

    // wave argmax reduce (max h, first index on ties)
#pragma unroll
    for (int off = 32; off > 0; off >>= 1) {
        const double oH   = __shfl_down(bestH, off, 64);
        const int    oIdx = __shfl_down(bestIdx, off, 64);
        const double oCs  = __shfl_down(bestCs, off, 64);
        if (oH > bestH || (oH == bestH && oIdx < bestIdx)) {
            bestH = oH; bestIdx = oIdx; bestCs = oCs;
        }
    }
    if (lane == 0) { redH[wv] = bestH; redIdx[wv] = bestIdx; redCs[wv] = bestCs; }
    __syncthreads();

    if (tid == 0 && blockIdx.x == 0) {
        double bH = redH[0], bCs = redCs[0];
        int bIdx = redIdx[0];
        for (int w = 1; w < 16; ++w) {
            if (redH[w] > bH || (redH[w] == bH && redIdx[w] < bIdx)) {
                bH = redH[w]; bIdx = redIdx[w]; bCs = redCs[w];
            }
        }
        const double Sb     = total2 - total1 * total1 / nf;
        const double optObj = (total2 - bH) / Sb;
        const double T      = (double)(bIdx + 1);
        out[0] = (float)(bCs / T + LAMB * optObj);
    }
}

// ---------------------------------------------------------------------------
extern "C" void kernel_launch(void* const* d_in, const int* in_sizes, int n_in,
                              void* d_out, int out_size, void* d_ws, size_t ws_size,
                              hipStream_t stream) {
    const float* inp = (const float*)d_in[0];
    const float* tgt = (const float*)d_in[1];
    float* errbuf = (float*)d_ws;   // 8192 f32 = 32 KB scratch

    rowerr_kernel<<<NROWS, 256, 0, stream>>>(inp, tgt, errbuf);
    drae_kernel<<<256, 1024, 0, stream>>>(errbuf, (float*)d_out);
}